// Round 7
// baseline (579.456 us; speedup 1.0000x reference)
//
#include <hip/hip_runtime.h>
#include <hip/hip_bf16.h>

// SurfaceLoss: 16x256x256 grid through 3->128->128->128->1 tanh MLP, MSE vs images.
// R17: INSTRUCTION-COUNT reduction, zero structural change (the only lever that
//      has ever paid: R11's recurrence -24 trans = -3us; all structural moves
//      R11b/R13/R15 regressed). tanh is NEVER materialized: tanh(z) = 1 - 2r,
//      r = rcp(exp2(KS z)+1). The affine (1 - 2.) is folded into operands:
//      - LDS stores r (layers 1,2); prep pre-scales w2t/w3t by -2*KS and emits
//        per-32k-tile rowsums KS*sum_k W[k][n] (slot per tile, no atomics);
//        acc init = KS*b + sum(rowparts)  [since W(1-2R) = sumW - 2 W R].
//      - epi3: s = sum w4 + sum r*(-2 w4)  (init-fold + fma).
//      Net: -96 VALU/thread (~8% of issue); MFMA/LDS/regs/grid identical to R14.
//      Frozen: R14 skeleton — 512 thr / wave=16ch / wf+w3f at 32V+32A cliff /
//      1 ds_read : 1 MFMA / exp2 recurrence / swapped MFMA D[ch][point] /
//      fence-free reduction / LDA 136 / v_perm pack2bf / prep LDS transpose.

#define BATCH 16
#define LDA 136                 // padded LDS row stride (bf16 elems)
#define STEP (256.0f / 255.0f)  // linspace(-128,128,256) step
#define KS 2.8853900817779268f  // 2*log2(e): tanh(z) = 1 - 2/(exp2(KS*z)+1)

typedef __bf16 v8bf __attribute__((ext_vector_type(8)));
typedef float  v4f  __attribute__((ext_vector_type(4)));

__device__ __forceinline__ unsigned short f2bf(float f) {   // round-nearest (prep only)
    unsigned int u = __float_as_uint(f);
    unsigned int r = (u + 0x7fffu + ((u >> 16) & 1u)) >> 16;
    return (unsigned short)r;
}

// hot-path pack: {hi16(b), hi16(a)} in ONE v_perm_b32 (bf16 truncation).
#if __has_builtin(__builtin_amdgcn_perm)
__device__ __forceinline__ unsigned int pack2bf(float a, float b) {
    return __builtin_amdgcn_perm(__float_as_uint(b), __float_as_uint(a), 0x07060302u);
}
#else
__device__ __forceinline__ unsigned int pack2bf(float a, float b) {
    return (__float_as_uint(a) >> 16) | (__float_as_uint(b) & 0xffff0000u);
}
#endif

// r = 1/(exp2(zk)+1); zk pre-scaled by KS. exp2(+big)->inf->rcp->0 exact.
__device__ __forceinline__ float sig_r(float zk) {
    return __builtin_amdgcn_rcpf(__builtin_amdgcn_exp2f(zk) + 1.f);
}

// ---- prep: W2,W3 (128x128 fp32 [k][n]) -> bf16 [n][k] scaled by -2*KS;
//      per-tile rowsums KS*sum_k W[k][n] -> rowbuf[mat][ktile][n];
//      LDS 32x32 tile transpose (R14); zeros partials + counter. ----
__global__ __launch_bounds__(256) void prep_kernel(
    const float* __restrict__ W2, const float* __restrict__ W3,
    unsigned short* __restrict__ w2t, unsigned short* __restrict__ w3t,
    float* __restrict__ partials, unsigned int* __restrict__ counter,
    float* __restrict__ rowbuf)
{
    __shared__ float t[32][33];

    const int bid = blockIdx.x;          // 32 blocks: bit4 = matrix, bits0..3 = tile
    const int tid = threadIdx.x;

    {   // workspace zeroing (8192 threads total cover 1024 partials + counter)
        int o = bid * 256 + tid;
        if (o < 1024) partials[o] = 0.f;
        if (o == 0) *counter = 0u;
    }

    const float* src          = (bid < 16) ? W2 : W3;
    unsigned short* dst       = (bid < 16) ? w2t : w3t;
    const int tl = bid & 15;
    const int tr = tl >> 2;              // k-tile (rows of src)
    const int tc = tl & 3;               // n-tile (cols of src)
    const int tx = tid & 31;
    const int ty = tid >> 5;             // 0..7

    // load 32x32 f32 tile, coalesced rows: t[a][b] = src[(tr*32+a)*128 + tc*32+b]
    #pragma unroll
    for (int i = 0; i < 4; ++i) {
        int a = i * 8 + ty;
        t[a][tx] = src[(tr * 32 + a) * 128 + tc * 32 + tx];
    }
    __syncthreads();

    // write transposed, scaled by -2*KS: dst[n*128+k]
    // LDS read t[tx][...]: column access, stride 33 -> conflict-free.
    #pragma unroll
    for (int i = 0; i < 4; ++i) {
        int nn = tc * 32 + i * 8 + ty;
        int kk = tr * 32 + tx;
        dst[nn * 128 + kk] = f2bf(t[tx][i * 8 + ty] * (-2.f * KS));
    }

    // per-tile rowsum over the 32 k's for each n: slot rowbuf[mat*512 + tr*128 + n]
    if (tid < 32) {
        float s = 0.f;
        #pragma unroll
        for (int a = 0; a < 32; ++a) s += t[a][tid];   // banks (a+tid)%32: conflict-free
        rowbuf[(bid >> 4) * 512 + tr * 128 + tc * 32 + tid] = KS * s;
    }
}

// ---- main: one block (512 thr, 8 waves) = 128 consecutive pixels of one image row ----
__global__ __launch_bounds__(512, 8) void main_kernel(
    const float* __restrict__ images,
    const float* __restrict__ W1, const float* __restrict__ b1,
    const float* __restrict__ b2, const float* __restrict__ b3,
    const float* __restrict__ W4, const float* __restrict__ b4,
    const int*   __restrict__ np,
    const unsigned short* __restrict__ w2t,
    const unsigned short* __restrict__ w3t,
    float* __restrict__ partials, unsigned int* __restrict__ counter,
    float* __restrict__ out, const float* __restrict__ rowbuf)
{
    __shared__ unsigned short A[128 * LDA];
    __shared__ float P[8][128];       // per-wave partial dots (16 chs each) per point
    __shared__ float red[8];
    __shared__ unsigned int isLastS;

    const int tid  = threadIdx.x;
    const int lane = tid & 63;
    const int w    = tid >> 6;        // wave 0..7, owns 16 channels
    const int l15  = lane & 15;
    const int quad = lane >> 4;

    const int bid = blockIdx.x;
    const int b   = bid >> 9;          // 512 blocks per image
    const int rem = bid & 511;
    const int r   = rem >> 1;          // image row (x index)
    const int c0  = (rem & 1) << 7;    // y base

    const float tv = (float)(b + np[0] * BATCH);
    const float xv = -128.f + (float)r * STEP;

    // ---- layer 1 (fp32, pre-scaled by KS): 4 cols x 8 points, e-RECURRENCE.
    //      Stores r = 1/(e+1) (NOT tanh) — the 1-2r affine is folded into w2t. ----
    {
        const int lo = tid & 31, hi = tid >> 5;
        const int j0 = lo * 4, p0 = hi * 8;
        float4 wx = *(const float4*)(W1 + j0);
        float4 wy = *(const float4*)(W1 + 128 + j0);
        float4 wt = *(const float4*)(W1 + 256 + j0);
        float4 bb = *(const float4*)(b1 + j0);
        const float yv0 = fmaf((float)(c0 + p0), STEP, -128.f);
        float z0 = fmaf(yv0, KS * wy.x, KS * fmaf(xv, wx.x, fmaf(tv, wt.x, bb.x)));
        float z1 = fmaf(yv0, KS * wy.y, KS * fmaf(xv, wx.y, fmaf(tv, wt.y, bb.y)));
        float z2 = fmaf(yv0, KS * wy.z, KS * fmaf(xv, wx.z, fmaf(tv, wt.z, bb.z)));
        float z3 = fmaf(yv0, KS * wy.w, KS * fmaf(xv, wx.w, fmaf(tv, wt.w, bb.w)));
        float e0 = __builtin_amdgcn_exp2f(z0);
        float e1 = __builtin_amdgcn_exp2f(z1);
        float e2 = __builtin_amdgcn_exp2f(z2);
        float e3 = __builtin_amdgcn_exp2f(z3);
        const float E0 = __builtin_amdgcn_exp2f(KS * STEP * wy.x);
        const float E1 = __builtin_amdgcn_exp2f(KS * STEP * wy.y);
        const float E2 = __builtin_amdgcn_exp2f(KS * STEP * wy.z);
        const float E3 = __builtin_amdgcn_exp2f(KS * STEP * wy.w);
        #pragma unroll
        for (int pi = 0; pi < 8; ++pi) {
            float r0 = __builtin_amdgcn_rcpf(e0 + 1.f);
            float r1 = __builtin_amdgcn_rcpf(e1 + 1.f);
            float r2 = __builtin_amdgcn_rcpf(e2 + 1.f);
            float r3 = __builtin_amdgcn_rcpf(e3 + 1.f);
            uint2 u = make_uint2(pack2bf(r0, r1), pack2bf(r2, r3));
            *(uint2*)&A[(p0 + pi) * LDA + j0] = u;   // 8B store, conflict-free
            e0 *= E0; e1 *= E1; e2 *= E2; e3 *= E3;
        }
    }
    __syncthreads();

    const int colw = w * 16 + l15;     // this lane's channel row (A-operand m index)
    const int ch4  = w * 16 + quad * 4; // this lane's 4-channel base in C/D layout

    // ---- W2 A-fragments from L2 ([n][k] layout, scaled -2*KS) ----
    v8bf wf[4];
    #pragma unroll
    for (int ks = 0; ks < 4; ++ks)
        wf[ks] = *(const v8bf*)(w2t + colw * 128 + ks * 32 + quad * 8);

    // ---- layer 2 MFMA, swapped: D[ch][point];
    //      acc init = KS*b2[ch] + KS*sum_k W2[k][ch]  (affine fold) ----
    v4f acc[8];
    {
        float4 bq = *(const float4*)(b2 + ch4);
        float4 s0 = *(const float4*)(rowbuf + ch4);
        float4 s1 = *(const float4*)(rowbuf + 128 + ch4);
        float4 s2 = *(const float4*)(rowbuf + 256 + ch4);
        float4 s3 = *(const float4*)(rowbuf + 384 + ch4);
        v4f ini = (v4f){fmaf(KS, bq.x, (s0.x + s1.x) + (s2.x + s3.x)),
                        fmaf(KS, bq.y, (s0.y + s1.y) + (s2.y + s3.y)),
                        fmaf(KS, bq.z, (s0.z + s1.z) + (s2.z + s3.z)),
                        fmaf(KS, bq.w, (s0.w + s1.w) + (s2.w + s3.w))};
        #pragma unroll
        for (int mt = 0; mt < 8; ++mt) acc[mt] = ini;
    }
    #pragma unroll
    for (int ks = 0; ks < 4; ++ks) {
        #pragma unroll
        for (int mt = 0; mt < 8; ++mt) {
            v8bf af = *(const v8bf*)&A[(mt * 16 + l15) * LDA + ks * 32 + quad * 8];
            acc[mt] = __builtin_amdgcn_mfma_f32_16x16x32_bf16(wf[ks], af, acc[mt], 0, 0, 0);
        }
    }

    // prefetch W3 A-fragments (same layout)
    v8bf w3f[4];
    #pragma unroll
    for (int ks = 0; ks < 4; ++ks)
        w3f[ks] = *(const v8bf*)(w3t + colw * 128 + ks * 32 + quad * 8);
    __syncthreads();   // all waves done reading A (R1)

    // ---- epilogue 2: r = 1/(exp2(acc)+1) -> A as R2[point][ch] ----
    #pragma unroll
    for (int mt = 0; mt < 8; ++mt) {
        uint2 u = make_uint2(pack2bf(sig_r(acc[mt][0]), sig_r(acc[mt][1])),
                             pack2bf(sig_r(acc[mt][2]), sig_r(acc[mt][3])));
        *(uint2*)&A[(mt * 16 + l15) * LDA + ch4] = u;   // 4 consecutive ch, 8B aligned
    }
    __syncthreads();

    // ---- layer 3 MFMA, swapped: acc init = KS*b3 + KS*rowsum(W3) ----
    {
        float4 bq = *(const float4*)(b3 + ch4);
        float4 s0 = *(const float4*)(rowbuf + 512 + ch4);
        float4 s1 = *(const float4*)(rowbuf + 512 + 128 + ch4);
        float4 s2 = *(const float4*)(rowbuf + 512 + 256 + ch4);
        float4 s3 = *(const float4*)(rowbuf + 512 + 384 + ch4);
        v4f ini = (v4f){fmaf(KS, bq.x, (s0.x + s1.x) + (s2.x + s3.x)),
                        fmaf(KS, bq.y, (s0.y + s1.y) + (s2.y + s3.y)),
                        fmaf(KS, bq.z, (s0.z + s1.z) + (s2.z + s3.z)),
                        fmaf(KS, bq.w, (s0.w + s1.w) + (s2.w + s3.w))};
        #pragma unroll
        for (int mt = 0; mt < 8; ++mt) acc[mt] = ini;
    }
    #pragma unroll
    for (int ks = 0; ks < 4; ++ks) {
        #pragma unroll
        for (int mt = 0; mt < 8; ++mt) {
            v8bf af = *(const v8bf*)&A[(mt * 16 + l15) * LDA + ks * 32 + quad * 8];
            acc[mt] = __builtin_amdgcn_mfma_f32_16x16x32_bf16(w3f[ks], af, acc[mt], 0, 0, 0);
        }
    }

    // ---- epilogue 3 + layer 4: s = sum w4 + sum r*(-2 w4), quad-butterfly ----
    {
        float4 w4q = *(const float4*)(W4 + ch4);
        const float m0 = -2.f * w4q.x, m1 = -2.f * w4q.y,
                    m2 = -2.f * w4q.z, m3 = -2.f * w4q.w;
        const float base = (w4q.x + w4q.y) + (w4q.z + w4q.w);
        #pragma unroll
        for (int mt = 0; mt < 8; ++mt) {
            float s = base;
            s = fmaf(sig_r(acc[mt][0]), m0, s);
            s = fmaf(sig_r(acc[mt][1]), m1, s);
            s = fmaf(sig_r(acc[mt][2]), m2, s);
            s = fmaf(sig_r(acc[mt][3]), m3, s);
            s += __shfl_xor(s, 16, 64);      // sum quads 0..3 (same point)
            s += __shfl_xor(s, 32, 64);
            if (quad == 0) P[w][mt * 16 + l15] = s;   // wave's 16-ch partial for point
        }
    }
    __syncthreads();

    // ---- loss: threads 0..127, one point each ----
    {
        float e2 = 0.f;
        if (tid < 128) {
            float s = b4[0];
            #pragma unroll
            for (int ww = 0; ww < 8; ++ww) s += P[ww][tid];
            float img = images[(b << 16) + (r << 8) + c0 + tid];
            float err = img - s;
            e2 = err * err;
        }
        #pragma unroll
        for (int off = 1; off < 64; off <<= 1)
            e2 += __shfl_xor(e2, off, 64);
        if (lane == 0 && tid < 128)
            atomicAdd(&partials[bid & 1023], e2);   // device-scope RMW (proven cheap)
    }

    // ---- fence-free last-block reduction (R7-proven) ----
    __syncthreads();
    if (tid == 0)
        isLastS = (atomicAdd(counter, 1u) == (unsigned)(gridDim.x - 1)) ? 1u : 0u;
    __syncthreads();
    if (isLastS) {
        float s = __hip_atomic_load(&partials[tid],       __ATOMIC_RELAXED, __HIP_MEMORY_SCOPE_AGENT)
                + __hip_atomic_load(&partials[tid + 512], __ATOMIC_RELAXED, __HIP_MEMORY_SCOPE_AGENT);
        #pragma unroll
        for (int off = 1; off < 64; off <<= 1)
            s += __shfl_xor(s, off, 64);
        if (lane == 0) red[w] = s;
        __syncthreads();
        if (tid == 0) {
            float tot = 0.f;
            #pragma unroll
            for (int i = 0; i < 8; ++i) tot += red[i];
            out[0] = tot * (1.f / 1048576.f);
        }
    }
}

extern "C" void kernel_launch(void* const* d_in, const int* in_sizes, int n_in,
                              void* d_out, int out_size, void* d_ws, size_t ws_size,
                              hipStream_t stream)
{
    const float* images = (const float*)d_in[0];
    const float* W1 = (const float*)d_in[1];
    const float* b1 = (const float*)d_in[2];
    const float* W2 = (const float*)d_in[3];
    const float* b2 = (const float*)d_in[4];
    const float* W3 = (const float*)d_in[5];
    const float* b3 = (const float*)d_in[6];
    const float* W4 = (const float*)d_in[7];
    const float* b4 = (const float*)d_in[8];
    const int*   np = (const int*)d_in[10];

    unsigned short* w2t = (unsigned short*)d_ws;                     // 32 KB
    unsigned short* w3t = w2t + 128 * 128;                           // 32 KB
    float* partials = (float*)((char*)d_ws + 65536);                 // 4 KB
    unsigned int* counter = (unsigned int*)((char*)d_ws + 65536 + 4096);
    float* rowbuf = (float*)((char*)d_ws + 65536 + 4096 + 64);       // 2*4*128 f32 = 4 KB

    prep_kernel<<<32, 256, 0, stream>>>(W2, W3, w2t, w3t, partials, counter, rowbuf);
    main_kernel<<<BATCH * 256 * 2, 512, 0, stream>>>(
        images, W1, b1, b2, b3, W4, b4, np, w2t, w3t, partials, counter,
        (float*)d_out, rowbuf);
}

// Round 8
// 195.590 us; speedup vs baseline: 2.9626x; 2.9626x over previous
//
#include <hip/hip_runtime.h>
#include <hip/hip_bf16.h>

// SurfaceLoss: 16x256x256 grid through 3->128->128->128->1 tanh MLP, MSE vs images.
// R18: FINAL REVERT to R14/R16 (best measured: main 137.0-137.5us, bench 191.4us,
//      reproduced 3x). Failure ledger of every hot-path perturbation attempted:
//      - R11: W refetched per-ks from L2 inside MFMA loop -> lockstep vmcnt stall
//        (184us, all pipes less busy).
//      - R13: dual-MFMA per LDS af read, W preloaded -> defeats compiler lgkmcnt
//        ds_read->MFMA pipelining (184us; conflicts halved, timing worse ->
//        conflicts are hidden, not critical).
//      - R15: 256-thr blocks, 2 sequential 16ch groups -> silent scratch spill
//        (+101MB HBM WRITE_SIZE, 243us).
//      - R17: store r=rcp(exp2+1) instead of tanh, affine folded into weights
//        (-96 VALU/thread) -> 519us: cycle counters prove identical work +425us
//        pure idle; suspected denormal-class values in the MFMA/bf16 path
//        (r has exact-0/denormal bands; tanh saturates to +-1 and never does).
//      Conclusion: sharp local optimum — 512 thr / wave=16ch / wf[4]+w3f[4] held
//      at the exact 32V+32A cliff / 1 ds_read : 1 MFMA / 4 desynced blocks/CU /
//      tanh values in [-1,1]. Only instruction-count reduction that preserved
//      value distributions ever paid (R11's exp2 recurrence, -3us).
//      Frozen: layer-1 exp2 recurrence, R9 swapped MFMA (D[ch][point]), fused
//      epi3+layer4, exp2+rcp tanh, fence-free last-block reduction, LDA 136,
//      KS folding, v_perm pack2bf, prep LDS-tile transpose.

#define BATCH 16
#define LDA 136                 // padded LDS row stride (bf16 elems)
#define STEP (256.0f / 255.0f)  // linspace(-128,128,256) step
#define KS 2.8853900817779268f  // 2*log2(e): tanh(z) = 1 - 2/(exp2(KS*z)+1)

typedef __bf16 v8bf __attribute__((ext_vector_type(8)));
typedef float  v4f  __attribute__((ext_vector_type(4)));

__device__ __forceinline__ unsigned short f2bf(float f) {   // round-nearest (prep only)
    unsigned int u = __float_as_uint(f);
    unsigned int r = (u + 0x7fffu + ((u >> 16) & 1u)) >> 16;
    return (unsigned short)r;
}

// hot-path pack: {hi16(b), hi16(a)} in ONE v_perm_b32 (bf16 truncation).
#if __has_builtin(__builtin_amdgcn_perm)
__device__ __forceinline__ unsigned int pack2bf(float a, float b) {
    return __builtin_amdgcn_perm(__float_as_uint(b), __float_as_uint(a), 0x07060302u);
}
#else
__device__ __forceinline__ unsigned int pack2bf(float a, float b) {
    return (__float_as_uint(a) >> 16) | (__float_as_uint(b) & 0xffff0000u);
}
#endif

// input pre-scaled by KS; R6 measured-best form. exp2(+big)->inf->rcp->0 exact.
__device__ __forceinline__ float tanh_pre(float zk) {
    float e = __builtin_amdgcn_exp2f(zk);
    float r = __builtin_amdgcn_rcpf(e + 1.f);
    return fmaf(-2.f, r, 1.f);
}

// ---- prep: W2,W3 (128x128 fp32 [k][n]) -> bf16 [n][k] pre-scaled by KS.
//      LDS 32x32 tile transpose: coalesced global read AND write, +1-pad
//      conflict-free LDS column read. Also zeros partials + counter. ----
__global__ __launch_bounds__(256) void prep_kernel(
    const float* __restrict__ W2, const float* __restrict__ W3,
    unsigned short* __restrict__ w2t, unsigned short* __restrict__ w3t,
    float* __restrict__ partials, unsigned int* __restrict__ counter)
{
    __shared__ float t[32][33];

    const int bid = blockIdx.x;          // 32 blocks: bit4 = matrix, bits0..3 = tile
    const int tid = threadIdx.x;

    {   // workspace zeroing (8192 threads total cover 1024 partials + counter)
        int o = bid * 256 + tid;
        if (o < 1024) partials[o] = 0.f;
        if (o == 0) *counter = 0u;
    }

    const float* src          = (bid < 16) ? W2 : W3;
    unsigned short* dst       = (bid < 16) ? w2t : w3t;
    const int tl = bid & 15;
    const int tr = tl >> 2;              // k-tile (rows of src)
    const int tc = tl & 3;               // n-tile (cols of src)
    const int tx = tid & 31;
    const int ty = tid >> 5;             // 0..7

    // load 32x32 f32 tile, coalesced rows: t[a][b] = src[(tr*32+a)*128 + tc*32+b]
    #pragma unroll
    for (int i = 0; i < 4; ++i) {
        int a = i * 8 + ty;
        t[a][tx] = src[(tr * 32 + a) * 128 + tc * 32 + tx];
    }
    __syncthreads();

    // write transposed, coalesced in k: dst[n*128+k] = f2bf(t[k'][n'] * KS)
    // LDS read t[tx][...]: column access, stride 33 -> bank (tx+c)%32, conflict-free.
    #pragma unroll
    for (int i = 0; i < 4; ++i) {
        int nn = tc * 32 + i * 8 + ty;
        int kk = tr * 32 + tx;
        dst[nn * 128 + kk] = f2bf(t[tx][i * 8 + ty] * KS);
    }
}

// ---- main: one block (512 thr, 8 waves) = 128 consecutive pixels of one image row ----
__global__ __launch_bounds__(512, 8) void main_kernel(
    const float* __restrict__ images,
    const float* __restrict__ W1, const float* __restrict__ b1,
    const float* __restrict__ b2, const float* __restrict__ b3,
    const float* __restrict__ W4, const float* __restrict__ b4,
    const int*   __restrict__ np,
    const unsigned short* __restrict__ w2t,
    const unsigned short* __restrict__ w3t,
    float* __restrict__ partials, unsigned int* __restrict__ counter,
    float* __restrict__ out)
{
    __shared__ unsigned short A[128 * LDA];
    __shared__ float P[8][128];       // per-wave partial dots (16 chs each) per point
    __shared__ float red[8];
    __shared__ unsigned int isLastS;

    const int tid  = threadIdx.x;
    const int lane = tid & 63;
    const int w    = tid >> 6;        // wave 0..7, owns 16 channels
    const int l15  = lane & 15;
    const int quad = lane >> 4;

    const int bid = blockIdx.x;
    const int b   = bid >> 9;          // 512 blocks per image
    const int rem = bid & 511;
    const int r   = rem >> 1;          // image row (x index)
    const int c0  = (rem & 1) << 7;    // y base

    const float tv = (float)(b + np[0] * BATCH);
    const float xv = -128.f + (float)r * STEP;

    // ---- layer 1 (fp32, pre-scaled by KS): 4 cols x 8 points, e-RECURRENCE ----
    {
        const int lo = tid & 31, hi = tid >> 5;
        const int j0 = lo * 4, p0 = hi * 8;
        float4 wx = *(const float4*)(W1 + j0);
        float4 wy = *(const float4*)(W1 + 128 + j0);
        float4 wt = *(const float4*)(W1 + 256 + j0);
        float4 bb = *(const float4*)(b1 + j0);
        const float yv0 = fmaf((float)(c0 + p0), STEP, -128.f);
        float z0 = fmaf(yv0, KS * wy.x, KS * fmaf(xv, wx.x, fmaf(tv, wt.x, bb.x)));
        float z1 = fmaf(yv0, KS * wy.y, KS * fmaf(xv, wx.y, fmaf(tv, wt.y, bb.y)));
        float z2 = fmaf(yv0, KS * wy.z, KS * fmaf(xv, wx.z, fmaf(tv, wt.z, bb.z)));
        float z3 = fmaf(yv0, KS * wy.w, KS * fmaf(xv, wx.w, fmaf(tv, wt.w, bb.w)));
        float e0 = __builtin_amdgcn_exp2f(z0);
        float e1 = __builtin_amdgcn_exp2f(z1);
        float e2 = __builtin_amdgcn_exp2f(z2);
        float e3 = __builtin_amdgcn_exp2f(z3);
        const float E0 = __builtin_amdgcn_exp2f(KS * STEP * wy.x);
        const float E1 = __builtin_amdgcn_exp2f(KS * STEP * wy.y);
        const float E2 = __builtin_amdgcn_exp2f(KS * STEP * wy.z);
        const float E3 = __builtin_amdgcn_exp2f(KS * STEP * wy.w);
        #pragma unroll
        for (int pi = 0; pi < 8; ++pi) {
            float h0 = fmaf(-2.f, __builtin_amdgcn_rcpf(e0 + 1.f), 1.f);
            float h1 = fmaf(-2.f, __builtin_amdgcn_rcpf(e1 + 1.f), 1.f);
            float h2 = fmaf(-2.f, __builtin_amdgcn_rcpf(e2 + 1.f), 1.f);
            float h3 = fmaf(-2.f, __builtin_amdgcn_rcpf(e3 + 1.f), 1.f);
            uint2 u = make_uint2(pack2bf(h0, h1), pack2bf(h2, h3));
            *(uint2*)&A[(p0 + pi) * LDA + j0] = u;   // 8B store, conflict-free
            e0 *= E0; e1 *= E1; e2 *= E2; e3 *= E3;
        }
    }
    __syncthreads();

    const int colw = w * 16 + l15;     // this lane's channel row (A-operand m index)
    const int ch4  = w * 16 + quad * 4; // this lane's 4-channel base in C/D layout

    // ---- W2 A-fragments from L2 ([n][k] layout = A-op [m=ch][k], pre-scaled) ----
    v8bf wf[4];
    #pragma unroll
    for (int ks = 0; ks < 4; ++ks)
        wf[ks] = *(const v8bf*)(w2t + colw * 128 + ks * 32 + quad * 8);

    // ---- layer 2 MFMA, swapped: D = W2K^T x H1^T -> D[ch][point];
    //      acc init = KS*b2[ch] (bias folded) ----
    v4f acc[8];
    {
        float4 b2q = *(const float4*)(b2 + ch4);
        v4f ini = (v4f){b2q.x * KS, b2q.y * KS, b2q.z * KS, b2q.w * KS};
        #pragma unroll
        for (int mt = 0; mt < 8; ++mt) acc[mt] = ini;
    }
    #pragma unroll
    for (int ks = 0; ks < 4; ++ks) {
        #pragma unroll
        for (int mt = 0; mt < 8; ++mt) {
            v8bf af = *(const v8bf*)&A[(mt * 16 + l15) * LDA + ks * 32 + quad * 8];
            acc[mt] = __builtin_amdgcn_mfma_f32_16x16x32_bf16(wf[ks], af, acc[mt], 0, 0, 0);
        }
    }

    // prefetch W3 A-fragments (same layout)
    v8bf w3f[4];
    #pragma unroll
    for (int ks = 0; ks < 4; ++ks)
        w3f[ks] = *(const v8bf*)(w3t + colw * 128 + ks * 32 + quad * 8);
    __syncthreads();   // all waves done reading A (H1)

    // ---- epilogue 2: tanh(acc) -> A as H2[point][ch], ONE b64 store per mt ----
    #pragma unroll
    for (int mt = 0; mt < 8; ++mt) {
        uint2 u = make_uint2(pack2bf(tanh_pre(acc[mt][0]), tanh_pre(acc[mt][1])),
                             pack2bf(tanh_pre(acc[mt][2]), tanh_pre(acc[mt][3])));
        *(uint2*)&A[(mt * 16 + l15) * LDA + ch4] = u;   // 4 consecutive ch, 8B aligned
    }
    __syncthreads();

    // ---- layer 3 MFMA, swapped: D[ch][point], acc init = KS*b3[ch] ----
    {
        float4 b3q = *(const float4*)(b3 + ch4);
        v4f ini = (v4f){b3q.x * KS, b3q.y * KS, b3q.z * KS, b3q.w * KS};
        #pragma unroll
        for (int mt = 0; mt < 8; ++mt) acc[mt] = ini;
    }
    #pragma unroll
    for (int ks = 0; ks < 4; ++ks) {
        #pragma unroll
        for (int mt = 0; mt < 8; ++mt) {
            v8bf af = *(const v8bf*)&A[(mt * 16 + l15) * LDA + ks * 32 + quad * 8];
            acc[mt] = __builtin_amdgcn_mfma_f32_16x16x32_bf16(w3f[ks], af, acc[mt], 0, 0, 0);
        }
    }

    // ---- epilogue 3 fused with layer 4: s = sum_rg tanh(acc)*W4[ch], quad-butterfly ----
    {
        float4 w4q = *(const float4*)(W4 + ch4);
        #pragma unroll
        for (int mt = 0; mt < 8; ++mt) {
            float s;
            s  = tanh_pre(acc[mt][0]) * w4q.x;
            s  = fmaf(tanh_pre(acc[mt][1]), w4q.y, s);
            s  = fmaf(tanh_pre(acc[mt][2]), w4q.z, s);
            s  = fmaf(tanh_pre(acc[mt][3]), w4q.w, s);
            s += __shfl_xor(s, 16, 64);      // sum quads 0..3 (same point)
            s += __shfl_xor(s, 32, 64);
            if (quad == 0) P[w][mt * 16 + l15] = s;   // wave's 16-ch partial for point
        }
    }
    __syncthreads();

    // ---- loss: threads 0..127, one point each ----
    {
        float e2 = 0.f;
        if (tid < 128) {
            float s = b4[0];
            #pragma unroll
            for (int ww = 0; ww < 8; ++ww) s += P[ww][tid];
            float img = images[(b << 16) + (r << 8) + c0 + tid];
            float err = img - s;
            e2 = err * err;
        }
        #pragma unroll
        for (int off = 1; off < 64; off <<= 1)
            e2 += __shfl_xor(e2, off, 64);
        if (lane == 0 && tid < 128)
            atomicAdd(&partials[bid & 1023], e2);   // device-scope RMW (proven cheap)
    }

    // ---- fence-free last-block reduction (R7-proven) ----
    __syncthreads();
    if (tid == 0)
        isLastS = (atomicAdd(counter, 1u) == (unsigned)(gridDim.x - 1)) ? 1u : 0u;
    __syncthreads();
    if (isLastS) {
        float s = __hip_atomic_load(&partials[tid],       __ATOMIC_RELAXED, __HIP_MEMORY_SCOPE_AGENT)
                + __hip_atomic_load(&partials[tid + 512], __ATOMIC_RELAXED, __HIP_MEMORY_SCOPE_AGENT);
        #pragma unroll
        for (int off = 1; off < 64; off <<= 1)
            s += __shfl_xor(s, off, 64);
        if (lane == 0) red[w] = s;
        __syncthreads();
        if (tid == 0) {
            float tot = 0.f;
            #pragma unroll
            for (int i = 0; i < 8; ++i) tot += red[i];
            out[0] = tot * (1.f / 1048576.f);
        }
    }
}

extern "C" void kernel_launch(void* const* d_in, const int* in_sizes, int n_in,
                              void* d_out, int out_size, void* d_ws, size_t ws_size,
                              hipStream_t stream)
{
    const float* images = (const float*)d_in[0];
    const float* W1 = (const float*)d_in[1];
    const float* b1 = (const float*)d_in[2];
    const float* W2 = (const float*)d_in[3];
    const float* b2 = (const float*)d_in[4];
    const float* W3 = (const float*)d_in[5];
    const float* b3 = (const float*)d_in[6];
    const float* W4 = (const float*)d_in[7];
    const float* b4 = (const float*)d_in[8];
    const int*   np = (const int*)d_in[10];

    unsigned short* w2t = (unsigned short*)d_ws;                     // 32 KB
    unsigned short* w3t = w2t + 128 * 128;                           // 32 KB
    float* partials = (float*)((char*)d_ws + 65536);                 // 4 KB
    unsigned int* counter = (unsigned int*)((char*)d_ws + 65536 + 4096);

    prep_kernel<<<32, 256, 0, stream>>>(W2, W3, w2t, w3t, partials, counter);
    main_kernel<<<BATCH * 256 * 2, 512, 0, stream>>>(
        images, W1, b1, b2, b3, W4, b4, np, w2t, w3t, partials, counter, (float*)d_out);
}